// Round 2
// baseline (1938.954 us; speedup 1.0000x reference)
//
#include <hip/hip_runtime.h>
#include <hip/hip_bf16.h>

// ---------------- model constants ----------------
static constexpr int SEQ   = 2048;
static constexpr int DM    = 2048;
static constexpr int NHEAD = 16;
static constexpr int NKVH  = 8;
static constexpr int HDIM  = 128;
static constexpr int FFN   = 6144;
static constexpr int NLAYER = 2;
static constexpr float EPSV = 1e-6f;
static constexpr int CHUNK = 2;   // q-heads per attention chunk

typedef __attribute__((ext_vector_type(8))) short bf16x8;
typedef __attribute__((ext_vector_type(4))) float f32x4;

__device__ __forceinline__ float wave_sum(float v) {
#pragma unroll
    for (int o = 32; o > 0; o >>= 1) v += __shfl_xor(v, o);
    return v;
}
__device__ __forceinline__ float wave_max(float v) {
#pragma unroll
    for (int o = 32; o > 0; o >>= 1) v = fmaxf(v, __shfl_xor(v, o));
    return v;
}

// async global->LDS, 16B per lane (m97 staging path)
__device__ __forceinline__ void gload16(const void* g, void* l) {
    __builtin_amdgcn_global_load_lds(
        (const __attribute__((address_space(1))) void*)g,
        (__attribute__((address_space(3))) void*)l,
        16, 0, 0);
}

// ---------------- f32 -> bf16 weight convert ----------------
__global__ void cvt_bf16_k(const float* __restrict__ in, __hip_bfloat16* __restrict__ out) {
    const long b = ((long)blockIdx.x * 256 + threadIdx.x) * 8;
    const float4 a0 = *(const float4*)(in + b);
    const float4 a1 = *(const float4*)(in + b + 4);
    union { bf16x8 v; __hip_bfloat16 h[8]; } u;
    u.h[0] = __float2bfloat16(a0.x); u.h[1] = __float2bfloat16(a0.y);
    u.h[2] = __float2bfloat16(a0.z); u.h[3] = __float2bfloat16(a0.w);
    u.h[4] = __float2bfloat16(a1.x); u.h[5] = __float2bfloat16(a1.y);
    u.h[6] = __float2bfloat16(a1.z); u.h[7] = __float2bfloat16(a1.w);
    *(bf16x8*)(out + b) = u.v;
}

// ---------------- embedding gather ----------------
__global__ void embed_k(const int* __restrict__ ids, const float* __restrict__ emb,
                        float* __restrict__ h) {
    const int s = blockIdx.x;
    const long src = (long)ids[s] * DM;
    for (int t = threadIdx.x; t < DM; t += 256)
        h[(long)s * DM + t] = emb[src + t];
}

// ---------------- RMSNorm (f32 in -> bf16 out) ----------------
__global__ void rmsnorm_k(const float* __restrict__ in, const float* __restrict__ g,
                          __hip_bfloat16* __restrict__ out) {
    const int row = blockIdx.x;
    const float* r = in + (long)row * DM;
    const int tid = threadIdx.x;
    float v[8];
    float ss = 0.f;
#pragma unroll
    for (int t = 0; t < 8; ++t) { v[t] = r[tid + t * 256]; ss += v[t] * v[t]; }
    ss = wave_sum(ss);
    __shared__ float sp[4];
    if ((tid & 63) == 0) sp[tid >> 6] = ss;
    __syncthreads();
    ss = sp[0] + sp[1] + sp[2] + sp[3];
    const float inv = rsqrtf(ss * (1.f / DM) + EPSV);
    __hip_bfloat16* o_ = out + (long)row * DM;
#pragma unroll
    for (int t = 0; t < 8; ++t) {
        const int j = tid + t * 256;
        o_[j] = __float2bfloat16(v[t] * inv * g[j]);
    }
}

// ---------------- per-head RMSNorm + RoPE (one wave per (s,head)) ----------------
__global__ void qknorm_rope_k(const float* __restrict__ in, const float* __restrict__ ns,
                              const float* __restrict__ cosT, const float* __restrict__ sinT,
                              __hip_bfloat16* __restrict__ out, int nheads, int rep) {
    const int idx = blockIdx.x * 4 + (threadIdx.x >> 6);
    const int lane = threadIdx.x & 63;
    const int s = idx / nheads;
    const int hh = idx - s * nheads;
    const float* r = in + (long)s * (nheads * HDIM) + hh * HDIM;
    const float x1 = r[lane];
    const float x2 = r[lane + 64];
    float ss = wave_sum(x1 * x1 + x2 * x2);
    const float inv = rsqrtf(ss * (1.f / HDIM) + EPSV);
    const float n1 = x1 * inv * ns[lane];
    const float n2 = x2 * inv * ns[lane + 64];
    const float c1 = cosT[s * HDIM + lane],      c2 = cosT[s * HDIM + 64 + lane];
    const float s1 = sinT[s * HDIM + lane],      s2 = sinT[s * HDIM + 64 + lane];
    const __hip_bfloat16 o1 = __float2bfloat16(n1 * c1 - n2 * s1);
    const __hip_bfloat16 o2 = __float2bfloat16(n2 * c2 + n1 * s2);
    for (int g = 0; g < rep; ++g) {
        __hip_bfloat16* w = out + ((long)(hh * rep + g) * SEQ + s) * HDIM;
        w[lane] = o1;
        w[lane + 64] = o2;
    }
}

// ---------------- V transpose+convert ----------------
__global__ void vtrans_k(const float* __restrict__ vf, __hip_bfloat16* __restrict__ vt) {
    __shared__ float tile[64][65];
    const int s0 = blockIdx.x * 64, d0 = blockIdx.y * 64, kv = blockIdx.z;
    const int lane = threadIdx.x & 63, part = threadIdx.x >> 6;
    for (int r = part; r < 64; r += 4)
        tile[r][lane] = vf[(long)(s0 + r) * (NKVH * HDIM) + kv * HDIM + d0 + lane];
    __syncthreads();
    for (int r = part; r < 64; r += 4) {
        const __hip_bfloat16 b = __float2bfloat16(tile[lane][r]);
        const long o0 = ((long)(2 * kv) * HDIM + d0 + r) * SEQ + s0 + lane;
        vt[o0] = b;
        vt[o0 + (long)HDIM * SEQ] = b;  // GQA-repeated copy
    }
}

// ---------------- causal softmax: f32 raw scores -> bf16 probs ----------------
__global__ void softmax_k(const float* __restrict__ sc, __hip_bfloat16* __restrict__ pr) {
    const int i = blockIdx.x;
    const long base = ((long)blockIdx.y * SEQ + i) * SEQ;
    const float* row = sc + base;
    __hip_bfloat16* orow = pr + base;
    const int tid = threadIdx.x;
    const int n = i + 1;
    const float scale = 0.0883883476483184405f;  // 1/sqrt(128)
    float m = -3.0e38f;
    for (int j = tid; j < n; j += 256) m = fmaxf(m, row[j]);
    m = wave_max(m);
    __shared__ float sm[4], ssum[4];
    const int wid = tid >> 6, lane = tid & 63;
    if (lane == 0) sm[wid] = m;
    __syncthreads();
    m = fmaxf(fmaxf(sm[0], sm[1]), fmaxf(sm[2], sm[3])) * scale;
    float s = 0.f;
    for (int j = tid; j < n; j += 256) s += __expf(row[j] * scale - m);
    s = wave_sum(s);
    if (lane == 0) ssum[wid] = s;
    __syncthreads();
    s = ssum[0] + ssum[1] + ssum[2] + ssum[3];
    const float inv = 1.f / s;
    for (int j = tid; j < SEQ; j += 256) {
        const float p = (j < n) ? __expf(row[j] * scale - m) * inv : 0.f;
        orow[j] = __float2bfloat16(p);
    }
}

// ---------------- bf16 MFMA GEMM, global_load_lds staging (m97 structure) ----------------
// C[M,N] = A[M,K] * B[N,K]^T. A,B bf16 row-major (K contiguous).
// OUT: 0 = f32 C; 1 = bf16 C; 2 = f32 C = acc + f32 Res; 3 = bf16 C = silu(bf16 Res)*acc.
// KMODE: 0 none; 1 causal block-skip (scores); 2 causal K-truncation (PV).
// 4 waves in 2x2 grid; wave tile (BM/2)x(BN/2) of 16x16x32 frags.
template <int BM, int BN, int OUT, int KMODE>
__global__ __launch_bounds__(256)
void gemm_lds(const __hip_bfloat16* __restrict__ A, const __hip_bfloat16* __restrict__ B,
              void* __restrict__ Cv, const void* __restrict__ Resv,
              int K, int ldC, long strideA, long strideB, long strideC) {
    constexpr int BK = 32;
    constexpr int WM = BM / 2, WN = BN / 2;
    constexpr int FM = WM / 16, FN = WN / 16;
    constexpr int CA = (BM * BK) / (256 * 8);   // 16B chunks per thread (A)
    constexpr int CB = (BN * BK) / (256 * 8);
    static_assert(CA >= 1 && CB >= 1, "tile too small");

    __shared__ __align__(16) __hip_bfloat16 sA[BM * BK];
    __shared__ __align__(16) __hip_bfloat16 sB[BN * BK];

    const int tid = threadIdx.x;
    const int lane = tid & 63;
    const int wid = tid >> 6;
    const int wr = wid >> 1;
    const int wc = wid & 1;

    const int row0 = blockIdx.y * BM;
    const int col0 = blockIdx.x * BN;
    if (KMODE == 1 && row0 + BM - 1 < col0) return;  // fully-masked score block

    const int bz = blockIdx.z;
    A += (long)bz * strideA;
    B += (long)bz * strideB;
    const long cOff = (long)bz * strideC;

    int nk = K / BK;
    if (KMODE == 2) { const int ke = row0 + BM; if (ke < K) nk = ke / BK; }

    f32x4 acc[FM][FN];
#pragma unroll
    for (int m = 0; m < FM; ++m)
#pragma unroll
        for (int n = 0; n < FN; ++n)
            acc[m][n] = (f32x4){0.f, 0.f, 0.f, 0.f};

    for (int kt = 0; kt < nk; ++kt) {
        const int k0 = kt * BK;
        // stage A,B tiles: LDS layout linear in chunk index (wave-uniform base + lane*16)
#pragma unroll
        for (int i = 0; i < CA; ++i) {
            const int c = i * 256 + tid;
            gload16(A + (long)(row0 + (c >> 2)) * K + (k0 + (c & 3) * 8), (char*)sA + c * 16);
        }
#pragma unroll
        for (int i = 0; i < CB; ++i) {
            const int c = i * 256 + tid;
            gload16(B + (long)(col0 + (c >> 2)) * K + (k0 + (c & 3) * 8), (char*)sB + c * 16);
        }
        __syncthreads();   // drains vmcnt: LDS tiles complete for all waves

        bf16x8 af[FM], bfg[FN];
#pragma unroll
        for (int m = 0; m < FM; ++m)
            af[m] = *(const bf16x8*)&sA[(wr * WM + m * 16 + (lane & 15)) * BK + (lane >> 4) * 8];
#pragma unroll
        for (int n = 0; n < FN; ++n)
            bfg[n] = *(const bf16x8*)&sB[(wc * WN + n * 16 + (lane & 15)) * BK + (lane >> 4) * 8];
#pragma unroll
        for (int m = 0; m < FM; ++m)
#pragma unroll
            for (int n = 0; n < FN; ++n)
                acc[m][n] = __builtin_amdgcn_mfma_f32_16x16x32_bf16(af[m], bfg[n], acc[m][n], 0, 0, 0);
        __syncthreads();   // all waves done reading before next stage overwrites
    }

    // epilogue: C/D layout col = lane&15, row = (lane>>4)*4 + reg (m89-verified)
#pragma unroll
    for (int m = 0; m < FM; ++m) {
#pragma unroll
        for (int n = 0; n < FN; ++n) {
            const int rb = row0 + wr * WM + m * 16 + (lane >> 4) * 4;
            const int cc = col0 + wc * WN + n * 16 + (lane & 15);
#pragma unroll
            for (int j = 0; j < 4; ++j) {
                const long idx = cOff + (long)(rb + j) * ldC + cc;
                const float v = acc[m][n][j];
                if constexpr (OUT == 0) {
                    ((float*)Cv)[idx] = v;
                } else if constexpr (OUT == 1) {
                    ((__hip_bfloat16*)Cv)[idx] = __float2bfloat16(v);
                } else if constexpr (OUT == 2) {
                    ((float*)Cv)[idx] = v + ((const float*)Resv)[idx];
                } else {  // OUT == 3: silu(gate)*up, bf16 in-place
                    const float g = __bfloat162float(((const __hip_bfloat16*)Resv)[idx]);
                    const float sg = g / (1.f + __expf(-g));
                    ((__hip_bfloat16*)Cv)[idx] = __float2bfloat16(sg * v);
                }
            }
        }
    }
}

// ---------------- host orchestration ----------------
extern "C" void kernel_launch(void* const* d_in, const int* in_sizes, int n_in,
                              void* d_out, int out_size, void* d_ws, size_t ws_size,
                              hipStream_t stream) {
    const int*   ids  = (const int*)d_in[0];
    const float* cosT = (const float*)d_in[2];
    const float* sinT = (const float*)d_in[3];
    const float* emb  = (const float*)d_in[4];
    const float* q_w  = (const float*)d_in[5];
    const float* k_w  = (const float*)d_in[6];
    const float* v_w  = (const float*)d_in[7];
    const float* o_w  = (const float*)d_in[8];
    const float* qn   = (const float*)d_in[9];
    const float* kn   = (const float*)d_in[10];
    const float* ln1  = (const float*)d_in[11];
    const float* ln2  = (const float*)d_in[12];
    const float* gw   = (const float*)d_in[13];
    const float* uw   = (const float*)d_in[14];
    const float* dw   = (const float*)d_in[15];

    char* W = (char*)d_ws;
    size_t off = 0;
    auto take = [&](size_t nb) { char* p = W + off; off += (nb + 255) & ~(size_t)255; return p; };

    float*          h      = (float*)          take((size_t)SEQ * DM * 4);
    __hip_bfloat16* x      = (__hip_bfloat16*) take((size_t)SEQ * DM * 2);
    float*          qf     = (float*)          take((size_t)SEQ * NHEAD * HDIM * 4);
    float*          kf     = (float*)          take((size_t)SEQ * NKVH * HDIM * 4);
    float*          vf     = (float*)          take((size_t)SEQ * NKVH * HDIM * 4);
    __hip_bfloat16* qb     = (__hip_bfloat16*) take((size_t)NHEAD * SEQ * HDIM * 2);
    __hip_bfloat16* kbr    = (__hip_bfloat16*) take((size_t)NHEAD * SEQ * HDIM * 2);
    __hip_bfloat16* vtr    = (__hip_bfloat16*) take((size_t)NHEAD * HDIM * SEQ * 2);
    __hip_bfloat16* ctx    = (__hip_bfloat16*) take((size_t)SEQ * NHEAD * HDIM * 2);
    float*          scores = (float*)          take((size_t)CHUNK * SEQ * SEQ * 4);
    __hip_bfloat16* probs  = (__hip_bfloat16*) take((size_t)CHUNK * SEQ * SEQ * 2);
    __hip_bfloat16* go     = (__hip_bfloat16*) take((size_t)SEQ * FFN * 2);
    __hip_bfloat16* wb     = (__hip_bfloat16*) take((size_t)FFN * DM * 2);  // converted weight
    if (off > ws_size) return;  // workspace too small: fail loudly

    auto cvt = [&](const float* src, long n) {
        cvt_bf16_k<<<(int)(n / 2048), 256, 0, stream>>>(src, wb);
    };

    embed_k<<<SEQ, 256, 0, stream>>>(ids, emb, h);

    for (int l = 0; l < NLAYER; ++l) {
        const float* qwl = q_w + (size_t)l * (NHEAD * HDIM) * DM;
        const float* kwl = k_w + (size_t)l * (NKVH * HDIM) * DM;
        const float* vwl = v_w + (size_t)l * (NKVH * HDIM) * DM;
        const float* owl = o_w + (size_t)l * DM * (NHEAD * HDIM);
        const float* gwl = gw  + (size_t)l * FFN * DM;
        const float* uwl = uw  + (size_t)l * FFN * DM;
        const float* dwl = dw  + (size_t)l * DM * FFN;

        rmsnorm_k<<<SEQ, 256, 0, stream>>>(h, ln1 + l * DM, x);

        cvt(qwl, (long)NHEAD * HDIM * DM);
        gemm_lds<128, 128, 0, 0><<<dim3(NHEAD * HDIM / 128, SEQ / 128, 1), 256, 0, stream>>>(
            x, wb, qf, nullptr, DM, NHEAD * HDIM, 0, 0, 0);
        cvt(kwl, (long)NKVH * HDIM * DM);
        gemm_lds<128, 64, 0, 0><<<dim3(NKVH * HDIM / 64, SEQ / 128, 1), 256, 0, stream>>>(
            x, wb, kf, nullptr, DM, NKVH * HDIM, 0, 0, 0);
        cvt(vwl, (long)NKVH * HDIM * DM);
        gemm_lds<128, 64, 0, 0><<<dim3(NKVH * HDIM / 64, SEQ / 128, 1), 256, 0, stream>>>(
            x, wb, vf, nullptr, DM, NKVH * HDIM, 0, 0, 0);

        qknorm_rope_k<<<SEQ * NHEAD / 4, 256, 0, stream>>>(qf, qn + l * HDIM, cosT, sinT, qb, NHEAD, 1);
        qknorm_rope_k<<<SEQ * NKVH / 4, 256, 0, stream>>>(kf, kn + l * HDIM, cosT, sinT, kbr, NKVH, 2);
        vtrans_k<<<dim3(SEQ / 64, HDIM / 64, NKVH), 256, 0, stream>>>(vf, vtr);

        for (int c = 0; c < NHEAD / CHUNK; ++c) {
            gemm_lds<128, 128, 0, 1><<<dim3(SEQ / 128, SEQ / 128, CHUNK), 256, 0, stream>>>(
                qb + (size_t)c * CHUNK * SEQ * HDIM,
                kbr + (size_t)c * CHUNK * SEQ * HDIM,
                scores, nullptr,
                HDIM, SEQ, (long)SEQ * HDIM, (long)SEQ * HDIM, (long)SEQ * SEQ);
            softmax_k<<<dim3(SEQ, CHUNK), 256, 0, stream>>>(scores, probs);
            gemm_lds<64, 64, 1, 2><<<dim3(HDIM / 64, SEQ / 64, CHUNK), 256, 0, stream>>>(
                probs,
                vtr + (size_t)c * CHUNK * HDIM * SEQ,
                ctx + (size_t)c * CHUNK * HDIM, nullptr,
                SEQ, NHEAD * HDIM, (long)SEQ * SEQ, (long)HDIM * SEQ, (long)HDIM);
        }

        cvt(owl, (long)DM * NHEAD * HDIM);
        gemm_lds<128, 128, 2, 0><<<dim3(DM / 128, SEQ / 128, 1), 256, 0, stream>>>(
            ctx, wb, h, h, NHEAD * HDIM, DM, 0, 0, 0);

        rmsnorm_k<<<SEQ, 256, 0, stream>>>(h, ln2 + l * DM, x);

        cvt(gwl, (long)FFN * DM);
        gemm_lds<128, 128, 1, 0><<<dim3(FFN / 128, SEQ / 128, 1), 256, 0, stream>>>(
            x, wb, go, nullptr, DM, FFN, 0, 0, 0);
        cvt(uwl, (long)FFN * DM);
        gemm_lds<128, 128, 3, 0><<<dim3(FFN / 128, SEQ / 128, 1), 256, 0, stream>>>(
            x, wb, go, go, DM, FFN, 0, 0, 0);   // go = silu(gate)*up, in place
        cvt(dwl, (long)DM * FFN);
        gemm_lds<128, 128, 2, 0><<<dim3(DM / 128, SEQ / 128, 1), 256, 0, stream>>>(
            go, wb, h, h, FFN, DM, 0, 0, 0);
    }

    hipMemcpyAsync(d_out, h, (size_t)out_size * sizeof(float), hipMemcpyDeviceToDevice, stream);
}

// Round 3
// 1592.095 us; speedup vs baseline: 1.2179x; 1.2179x over previous
//
#include <hip/hip_runtime.h>
#include <hip/hip_bf16.h>

// ---------------- model constants ----------------
static constexpr int SEQ   = 2048;
static constexpr int DM    = 2048;
static constexpr int NHEAD = 16;
static constexpr int NKVH  = 8;
static constexpr int HDIM  = 128;
static constexpr int FFN   = 6144;
static constexpr int NLAYER = 2;
static constexpr float EPSV = 1e-6f;
static constexpr int CHUNK = 8;   // q-heads per attention chunk
static constexpr int QKVN  = NHEAD * HDIM + 2 * NKVH * HDIM;  // 4096 fused QKV cols

typedef __attribute__((ext_vector_type(8))) short bf16x8;
typedef __attribute__((ext_vector_type(4))) float f32x4;

__device__ __forceinline__ float wave_sum(float v) {
#pragma unroll
    for (int o = 32; o > 0; o >>= 1) v += __shfl_xor(v, o);
    return v;
}
__device__ __forceinline__ float wave_max(float v) {
#pragma unroll
    for (int o = 32; o > 0; o >>= 1) v = fmaxf(v, __shfl_xor(v, o));
    return v;
}

// async global->LDS, 16B per lane
__device__ __forceinline__ void gload16(const void* g, void* l) {
    __builtin_amdgcn_global_load_lds(
        (const __attribute__((address_space(1))) void*)g,
        (__attribute__((address_space(3))) void*)l,
        16, 0, 0);
}

// ---------------- f32 -> bf16 weight convert ----------------
__global__ void cvt_bf16_k(const float* __restrict__ in, __hip_bfloat16* __restrict__ out) {
    const long b = ((long)blockIdx.x * 256 + threadIdx.x) * 8;
    const float4 a0 = *(const float4*)(in + b);
    const float4 a1 = *(const float4*)(in + b + 4);
    union { bf16x8 v; __hip_bfloat16 h[8]; } u;
    u.h[0] = __float2bfloat16(a0.x); u.h[1] = __float2bfloat16(a0.y);
    u.h[2] = __float2bfloat16(a0.z); u.h[3] = __float2bfloat16(a0.w);
    u.h[4] = __float2bfloat16(a1.x); u.h[5] = __float2bfloat16(a1.y);
    u.h[6] = __float2bfloat16(a1.z); u.h[7] = __float2bfloat16(a1.w);
    *(bf16x8*)(out + b) = u.v;
}

// ---------------- embedding gather ----------------
__global__ void embed_k(const int* __restrict__ ids, const float* __restrict__ emb,
                        float* __restrict__ h) {
    const int s = blockIdx.x;
    const long src = (long)ids[s] * DM;
    for (int t = threadIdx.x; t < DM; t += 256)
        h[(long)s * DM + t] = emb[src + t];
}

// ---------------- RMSNorm (f32 in -> bf16 out) ----------------
__global__ void rmsnorm_k(const float* __restrict__ in, const float* __restrict__ g,
                          __hip_bfloat16* __restrict__ out) {
    const int row = blockIdx.x;
    const float* r = in + (long)row * DM;
    const int tid = threadIdx.x;
    float v[8];
    float ss = 0.f;
#pragma unroll
    for (int t = 0; t < 8; ++t) { v[t] = r[tid + t * 256]; ss += v[t] * v[t]; }
    ss = wave_sum(ss);
    __shared__ float sp[4];
    if ((tid & 63) == 0) sp[tid >> 6] = ss;
    __syncthreads();
    ss = sp[0] + sp[1] + sp[2] + sp[3];
    const float inv = rsqrtf(ss * (1.f / DM) + EPSV);
    __hip_bfloat16* o_ = out + (long)row * DM;
#pragma unroll
    for (int t = 0; t < 8; ++t) {
        const int j = tid + t * 256;
        o_[j] = __float2bfloat16(v[t] * inv * g[j]);
    }
}

// ---------------- per-head RMSNorm + RoPE (one wave per (s,head)) ----------------
// in: [s][inStride] f32, head row at inOff + hh*HDIM. out: [head*rep+g][s][128] bf16.
__global__ void qknorm_rope_k(const float* __restrict__ in, int inStride, int inOff,
                              const float* __restrict__ ns,
                              const float* __restrict__ cosT, const float* __restrict__ sinT,
                              __hip_bfloat16* __restrict__ out, int nheads, int rep) {
    const int idx = blockIdx.x * 4 + (threadIdx.x >> 6);
    const int lane = threadIdx.x & 63;
    const int s = idx / nheads;
    const int hh = idx - s * nheads;
    const float* r = in + (long)s * inStride + inOff + hh * HDIM;
    const float x1 = r[lane];
    const float x2 = r[lane + 64];
    float ss = wave_sum(x1 * x1 + x2 * x2);
    const float inv = rsqrtf(ss * (1.f / HDIM) + EPSV);
    const float n1 = x1 * inv * ns[lane];
    const float n2 = x2 * inv * ns[lane + 64];
    const float c1 = cosT[s * HDIM + lane],      c2 = cosT[s * HDIM + 64 + lane];
    const float s1 = sinT[s * HDIM + lane],      s2 = sinT[s * HDIM + 64 + lane];
    const __hip_bfloat16 o1 = __float2bfloat16(n1 * c1 - n2 * s1);
    const __hip_bfloat16 o2 = __float2bfloat16(n2 * c2 + n1 * s2);
    for (int g = 0; g < rep; ++g) {
        __hip_bfloat16* w = out + ((long)(hh * rep + g) * SEQ + s) * HDIM;
        w[lane] = o1;
        w[lane + 64] = o2;
    }
}

// ---------------- V transpose+convert (strided f32 src -> vt [qhead][d][s] bf16, GQA-repeated) --------
__global__ void vtrans_k(const float* __restrict__ vf, int rowStride, int colOff,
                         __hip_bfloat16* __restrict__ vt) {
    __shared__ float tile[64][65];
    const int s0 = blockIdx.x * 64, d0 = blockIdx.y * 64, kv = blockIdx.z;
    const int lane = threadIdx.x & 63, part = threadIdx.x >> 6;
    for (int r = part; r < 64; r += 4)
        tile[r][lane] = vf[(long)(s0 + r) * rowStride + colOff + kv * HDIM + d0 + lane];
    __syncthreads();
    for (int r = part; r < 64; r += 4) {
        const __hip_bfloat16 b = __float2bfloat16(tile[lane][r]);
        const long o0 = ((long)(2 * kv) * HDIM + d0 + r) * SEQ + s0 + lane;
        vt[o0] = b;
        vt[o0 + (long)HDIM * SEQ] = b;  // GQA-repeated copy
    }
}

// ---------------- causal softmax: f32 raw scores -> bf16 probs ----------------
__global__ void softmax_k(const float* __restrict__ sc, __hip_bfloat16* __restrict__ pr) {
    const int i = blockIdx.x;
    const long base = ((long)blockIdx.y * SEQ + i) * SEQ;
    const float* row = sc + base;
    __hip_bfloat16* orow = pr + base;
    const int tid = threadIdx.x;
    const int n = i + 1;
    const float scale = 0.0883883476483184405f;  // 1/sqrt(128)
    float m = -3.0e38f;
    for (int j = tid; j < n; j += 256) m = fmaxf(m, row[j]);
    m = wave_max(m);
    __shared__ float sm[4], ssum[4];
    const int wid = tid >> 6, lane = tid & 63;
    if (lane == 0) sm[wid] = m;
    __syncthreads();
    m = fmaxf(fmaxf(sm[0], sm[1]), fmaxf(sm[2], sm[3])) * scale;
    float s = 0.f;
    for (int j = tid; j < n; j += 256) s += __expf(row[j] * scale - m);
    s = wave_sum(s);
    if (lane == 0) ssum[wid] = s;
    __syncthreads();
    s = ssum[0] + ssum[1] + ssum[2] + ssum[3];
    const float inv = 1.f / s;
    for (int j = tid; j < SEQ; j += 256) {
        const float p = (j < n) ? __expf(row[j] * scale - m) * inv : 0.f;
        orow[j] = __float2bfloat16(p);
    }
}

// ---------------- bf16 MFMA GEMM, double-buffered global_load_lds (T3-minimum 2-phase) --------
// C[M,N] = A[M,K] * B[N,K]^T.  A,B bf16 row-major with row stride exactly K.
// OUT: 0 = f32 C; 1 = bf16 C; 2 = f32 C = acc + f32 Res; 3 = bf16 C = silu(bf16 Res)*acc.
// KMODE: 0 none; 1 causal block-skip (scores); 2 causal K-truncation (PV).
// 4 waves, 2x2 grid; wave tile (BM/2)x(BN/2); BK=64 (2 k-slices of 16x16x32).
template <int BM, int BN, int OUT, int KMODE>
__global__ __launch_bounds__(256)
void gemm_db(const __hip_bfloat16* __restrict__ A, const __hip_bfloat16* __restrict__ B,
             void* __restrict__ Cv, const void* __restrict__ Resv,
             int K, int ldC, long strideA, long strideB, long strideC) {
    constexpr int BK = 64;
    constexpr int WM = BM / 2, WN = BN / 2;
    constexpr int FM = WM / 16, FN = WN / 16;
    constexpr int CA = (BM * BK) / (256 * 8);   // 16B chunks per thread (A)
    constexpr int CB = (BN * BK) / (256 * 8);
    static_assert(CA >= 1 && CB >= 1, "tile too small");

    __shared__ __align__(16) __hip_bfloat16 sA[2][BM * BK];
    __shared__ __align__(16) __hip_bfloat16 sB[2][BN * BK];

    const int tid = threadIdx.x;
    const int lane = tid & 63;
    const int wid = tid >> 6;
    const int wr = wid >> 1;
    const int wc = wid & 1;

    const int row0 = blockIdx.y * BM;
    const int col0 = blockIdx.x * BN;
    if (KMODE == 1 && row0 + BM - 1 < col0) return;  // fully-masked score block

    const int bz = blockIdx.z;
    A += (long)bz * strideA;
    B += (long)bz * strideB;
    const long cOff = (long)bz * strideC;

    int nk = K / BK;
    if (KMODE == 2) { const int ke = row0 + BM; if (ke < K) nk = ke / BK; }

    f32x4 acc[FM][FN];
#pragma unroll
    for (int m = 0; m < FM; ++m)
#pragma unroll
        for (int n = 0; n < FN; ++n)
            acc[m][n] = (f32x4){0.f, 0.f, 0.f, 0.f};

    auto stage = [&](int buf, int kt) {
        const int k0 = kt * BK;
#pragma unroll
        for (int i = 0; i < CA; ++i) {
            const int c = i * 256 + tid;                       // 16B chunk: row c>>3, col (c&7)*8
            gload16(A + (long)(row0 + (c >> 3)) * K + (k0 + (c & 7) * 8),
                    (char*)&sA[buf][0] + c * 16);
        }
#pragma unroll
        for (int i = 0; i < CB; ++i) {
            const int c = i * 256 + tid;
            gload16(B + (long)(col0 + (c >> 3)) * K + (k0 + (c & 7) * 8),
                    (char*)&sB[buf][0] + c * 16);
        }
    };

    stage(0, 0);
    __syncthreads();     // drains vmcnt(0): buf0 complete

    int cur = 0;
    for (int kt = 0; kt < nk; ++kt) {
        if (kt + 1 < nk) stage(cur ^ 1, kt + 1);   // async prefetch next K-tile

        bf16x8 af[FM][2], bfr[FN][2];
#pragma unroll
        for (int ks = 0; ks < 2; ++ks) {
#pragma unroll
            for (int m = 0; m < FM; ++m)
                af[m][ks] = *(const bf16x8*)&sA[cur][(wr * WM + m * 16 + (lane & 15)) * BK + ks * 32 + (lane >> 4) * 8];
#pragma unroll
            for (int n = 0; n < FN; ++n)
                bfr[n][ks] = *(const bf16x8*)&sB[cur][(wc * WN + n * 16 + (lane & 15)) * BK + ks * 32 + (lane >> 4) * 8];
        }
#pragma unroll
        for (int ks = 0; ks < 2; ++ks)
#pragma unroll
            for (int m = 0; m < FM; ++m)
#pragma unroll
                for (int n = 0; n < FN; ++n)
                    acc[m][n] = __builtin_amdgcn_mfma_f32_16x16x32_bf16(af[m][ks], bfr[n][ks], acc[m][n], 0, 0, 0);

        __syncthreads();   // all waves done reading buf[cur]; prefetch into buf[cur^1] landed
        cur ^= 1;
    }

    // epilogue: C/D layout col = lane&15, row = (lane>>4)*4 + reg (m89-verified)
#pragma unroll
    for (int m = 0; m < FM; ++m) {
#pragma unroll
        for (int n = 0; n < FN; ++n) {
            const int rb = row0 + wr * WM + m * 16 + (lane >> 4) * 4;
            const int cc = col0 + wc * WN + n * 16 + (lane & 15);
#pragma unroll
            for (int j = 0; j < 4; ++j) {
                const long idx = cOff + (long)(rb + j) * ldC + cc;
                const float v = acc[m][n][j];
                if constexpr (OUT == 0) {
                    ((float*)Cv)[idx] = v;
                } else if constexpr (OUT == 1) {
                    ((__hip_bfloat16*)Cv)[idx] = __float2bfloat16(v);
                } else if constexpr (OUT == 2) {
                    ((float*)Cv)[idx] = v + ((const float*)Resv)[idx];
                } else {  // OUT == 3: silu(gate)*up, bf16 in-place
                    const float g = __bfloat162float(((const __hip_bfloat16*)Resv)[idx]);
                    const float sg = g / (1.f + __expf(-g));
                    ((__hip_bfloat16*)Cv)[idx] = __float2bfloat16(sg * v);
                }
            }
        }
    }
}

// ---------------- host orchestration ----------------
extern "C" void kernel_launch(void* const* d_in, const int* in_sizes, int n_in,
                              void* d_out, int out_size, void* d_ws, size_t ws_size,
                              hipStream_t stream) {
    const int*   ids  = (const int*)d_in[0];
    const float* cosT = (const float*)d_in[2];
    const float* sinT = (const float*)d_in[3];
    const float* emb  = (const float*)d_in[4];
    const float* q_w  = (const float*)d_in[5];
    const float* k_w  = (const float*)d_in[6];
    const float* v_w  = (const float*)d_in[7];
    const float* o_w  = (const float*)d_in[8];
    const float* qn   = (const float*)d_in[9];
    const float* kn   = (const float*)d_in[10];
    const float* ln1  = (const float*)d_in[11];
    const float* ln2  = (const float*)d_in[12];
    const float* gw   = (const float*)d_in[13];
    const float* uw   = (const float*)d_in[14];
    const float* dw   = (const float*)d_in[15];

    char* W = (char*)d_ws;
    size_t off = 0;
    auto take = [&](size_t nb) { char* p = W + off; off += (nb + 255) & ~(size_t)255; return p; };

    // persistent bf16 weights (converted once per launch)
    __hip_bfloat16* wqkv = (__hip_bfloat16*) take((size_t)NLAYER * QKVN * DM * 2);   // [L][4096][2048]
    __hip_bfloat16* wo   = (__hip_bfloat16*) take((size_t)NLAYER * DM * (NHEAD * HDIM) * 2);
    __hip_bfloat16* wg   = (__hip_bfloat16*) take((size_t)NLAYER * FFN * DM * 2);
    __hip_bfloat16* wu   = (__hip_bfloat16*) take((size_t)NLAYER * FFN * DM * 2);
    __hip_bfloat16* wd   = (__hip_bfloat16*) take((size_t)NLAYER * DM * FFN * 2);
    // activations
    float*          h      = (float*)          take((size_t)SEQ * DM * 4);
    __hip_bfloat16* x      = (__hip_bfloat16*) take((size_t)SEQ * DM * 2);
    float*          qkvf   = (float*)          take((size_t)SEQ * QKVN * 4);        // [s][4096]
    __hip_bfloat16* qb     = (__hip_bfloat16*) take((size_t)NHEAD * SEQ * HDIM * 2);
    __hip_bfloat16* kbr    = (__hip_bfloat16*) take((size_t)NHEAD * SEQ * HDIM * 2);
    __hip_bfloat16* vtr    = (__hip_bfloat16*) take((size_t)NHEAD * HDIM * SEQ * 2);
    __hip_bfloat16* ctx    = (__hip_bfloat16*) take((size_t)SEQ * NHEAD * HDIM * 2);
    float*          scores = (float*)          take((size_t)CHUNK * SEQ * SEQ * 4);
    __hip_bfloat16* probs  = (__hip_bfloat16*) take((size_t)CHUNK * SEQ * SEQ * 2);
    __hip_bfloat16* go     = (__hip_bfloat16*) take((size_t)SEQ * FFN * 2);
    if (off > ws_size) return;  // workspace too small: fail loudly (output stays zero/poison)

    auto cvt = [&](const float* src, __hip_bfloat16* dst, long n) {
        cvt_bf16_k<<<(int)(n / 2048), 256, 0, stream>>>(src, dst);
    };

    // ---- convert all weights up front; QKV concatenated per layer ----
    for (int l = 0; l < NLAYER; ++l) {
        __hip_bfloat16* base = wqkv + (size_t)l * QKVN * DM;
        cvt(q_w + (size_t)l * (NHEAD * HDIM) * DM, base,                              (long)(NHEAD * HDIM) * DM);
        cvt(k_w + (size_t)l * (NKVH * HDIM) * DM,  base + (size_t)(NHEAD * HDIM) * DM, (long)(NKVH * HDIM) * DM);
        cvt(v_w + (size_t)l * (NKVH * HDIM) * DM,  base + (size_t)(NHEAD * HDIM + NKVH * HDIM) * DM, (long)(NKVH * HDIM) * DM);
    }
    cvt(o_w, wo, (long)NLAYER * DM * (NHEAD * HDIM));
    cvt(gw,  wg, (long)NLAYER * FFN * DM);
    cvt(uw,  wu, (long)NLAYER * FFN * DM);
    cvt(dw,  wd, (long)NLAYER * DM * FFN);

    embed_k<<<SEQ, 256, 0, stream>>>(ids, emb, h);

    for (int l = 0; l < NLAYER; ++l) {
        rmsnorm_k<<<SEQ, 256, 0, stream>>>(h, ln1 + l * DM, x);

        // fused QKV projection: [2048][4096] f32
        gemm_db<128, 128, 0, 0><<<dim3(QKVN / 128, SEQ / 128, 1), 256, 0, stream>>>(
            x, wqkv + (size_t)l * QKVN * DM, qkvf, nullptr, DM, QKVN, 0, 0, 0);

        qknorm_rope_k<<<SEQ * NHEAD / 4, 256, 0, stream>>>(
            qkvf, QKVN, 0, qn + l * HDIM, cosT, sinT, qb, NHEAD, 1);
        qknorm_rope_k<<<SEQ * NKVH / 4, 256, 0, stream>>>(
            qkvf, QKVN, NHEAD * HDIM, kn + l * HDIM, cosT, sinT, kbr, NKVH, 2);
        vtrans_k<<<dim3(SEQ / 64, HDIM / 64, NKVH), 256, 0, stream>>>(
            qkvf, QKVN, NHEAD * HDIM + NKVH * HDIM, vtr);

        for (int c = 0; c < NHEAD / CHUNK; ++c) {
            gemm_db<128, 128, 0, 1><<<dim3(SEQ / 128, SEQ / 128, CHUNK), 256, 0, stream>>>(
                qb + (size_t)c * CHUNK * SEQ * HDIM,
                kbr + (size_t)c * CHUNK * SEQ * HDIM,
                scores, nullptr,
                HDIM, SEQ, (long)SEQ * HDIM, (long)SEQ * HDIM, (long)SEQ * SEQ);
            softmax_k<<<dim3(SEQ, CHUNK), 256, 0, stream>>>(scores, probs);
            gemm_db<128, 128, 1, 2><<<dim3(HDIM / 128, SEQ / 128, CHUNK), 256, 0, stream>>>(
                probs,
                vtr + (size_t)c * CHUNK * HDIM * SEQ,
                ctx + (size_t)c * CHUNK * HDIM, nullptr,
                SEQ, NHEAD * HDIM, (long)SEQ * SEQ, (long)HDIM * SEQ, (long)HDIM);
        }

        gemm_db<128, 128, 2, 0><<<dim3(DM / 128, SEQ / 128, 1), 256, 0, stream>>>(
            ctx, wo + (size_t)l * DM * (NHEAD * HDIM), h, h, NHEAD * HDIM, DM, 0, 0, 0);

        rmsnorm_k<<<SEQ, 256, 0, stream>>>(h, ln2 + l * DM, x);

        gemm_db<128, 128, 1, 0><<<dim3(FFN / 128, SEQ / 128, 1), 256, 0, stream>>>(
            x, wg + (size_t)l * FFN * DM, go, nullptr, DM, FFN, 0, 0, 0);
        gemm_db<128, 128, 3, 0><<<dim3(FFN / 128, SEQ / 128, 1), 256, 0, stream>>>(
            x, wu + (size_t)l * FFN * DM, go, go, DM, FFN, 0, 0, 0);   // go = silu(gate)*up
        gemm_db<128, 128, 2, 0><<<dim3(DM / 128, SEQ / 128, 1), 256, 0, stream>>>(
            go, wd + (size_t)l * DM * FFN, h, h, FFN, DM, 0, 0, 0);
    }

    hipMemcpyAsync(d_out, h, (size_t)out_size * sizeof(float), hipMemcpyDeviceToDevice, stream);
}

// Round 4
// 1512.468 us; speedup vs baseline: 1.2820x; 1.0526x over previous
//
#include <hip/hip_runtime.h>
#include <hip/hip_bf16.h>

// ---------------- model constants ----------------
static constexpr int SEQ   = 2048;
static constexpr int DM    = 2048;
static constexpr int NHEAD = 16;
static constexpr int NKVH  = 8;
static constexpr int HDIM  = 128;
static constexpr int FFN   = 6144;
static constexpr int NLAYER = 2;
static constexpr float EPSV = 1e-6f;
static constexpr int CHUNK = 8;   // q-heads per attention chunk
static constexpr int QKVN  = NHEAD * HDIM + 2 * NKVH * HDIM;  // 4096 fused QKV cols

typedef __attribute__((ext_vector_type(8))) short bf16x8;
typedef __attribute__((ext_vector_type(4))) float f32x4;

__device__ __forceinline__ float wave_sum(float v) {
#pragma unroll
    for (int o = 32; o > 0; o >>= 1) v += __shfl_xor(v, o);
    return v;
}
__device__ __forceinline__ float wave_max(float v) {
#pragma unroll
    for (int o = 32; o > 0; o >>= 1) v = fmaxf(v, __shfl_xor(v, o));
    return v;
}

// async global->LDS, 16B per lane
__device__ __forceinline__ void gload16(const void* g, void* l) {
    __builtin_amdgcn_global_load_lds(
        (const __attribute__((address_space(1))) void*)g,
        (__attribute__((address_space(3))) void*)l,
        16, 0, 0);
}

// ---------------- f32 -> bf16 weight convert ----------------
__global__ void cvt_bf16_k(const float* __restrict__ in, __hip_bfloat16* __restrict__ out) {
    const long b = ((long)blockIdx.x * 256 + threadIdx.x) * 8;
    const float4 a0 = *(const float4*)(in + b);
    const float4 a1 = *(const float4*)(in + b + 4);
    union { bf16x8 v; __hip_bfloat16 h[8]; } u;
    u.h[0] = __float2bfloat16(a0.x); u.h[1] = __float2bfloat16(a0.y);
    u.h[2] = __float2bfloat16(a0.z); u.h[3] = __float2bfloat16(a0.w);
    u.h[4] = __float2bfloat16(a1.x); u.h[5] = __float2bfloat16(a1.y);
    u.h[6] = __float2bfloat16(a1.z); u.h[7] = __float2bfloat16(a1.w);
    *(bf16x8*)(out + b) = u.v;
}

// ---------------- embedding gather ----------------
__global__ void embed_k(const int* __restrict__ ids, const float* __restrict__ emb,
                        float* __restrict__ h) {
    const int s = blockIdx.x;
    const long src = (long)ids[s] * DM;
    for (int t = threadIdx.x; t < DM; t += 256)
        h[(long)s * DM + t] = emb[src + t];
}

// ---------------- RMSNorm (f32 in -> bf16 out) ----------------
__global__ void rmsnorm_k(const float* __restrict__ in, const float* __restrict__ g,
                          __hip_bfloat16* __restrict__ out) {
    const int row = blockIdx.x;
    const float* r = in + (long)row * DM;
    const int tid = threadIdx.x;
    float v[8];
    float ss = 0.f;
#pragma unroll
    for (int t = 0; t < 8; ++t) { v[t] = r[tid + t * 256]; ss += v[t] * v[t]; }
    ss = wave_sum(ss);
    __shared__ float sp[4];
    if ((tid & 63) == 0) sp[tid >> 6] = ss;
    __syncthreads();
    ss = sp[0] + sp[1] + sp[2] + sp[3];
    const float inv = rsqrtf(ss * (1.f / DM) + EPSV);
    __hip_bfloat16* o_ = out + (long)row * DM;
#pragma unroll
    for (int t = 0; t < 8; ++t) {
        const int j = tid + t * 256;
        o_[j] = __float2bfloat16(v[t] * inv * g[j]);
    }
}

// ---------------- per-head RMSNorm + RoPE (one wave per (s,head)) ----------------
__global__ void qknorm_rope_k(const float* __restrict__ in, int inStride, int inOff,
                              const float* __restrict__ ns,
                              const float* __restrict__ cosT, const float* __restrict__ sinT,
                              __hip_bfloat16* __restrict__ out, int nheads, int rep) {
    const int idx = blockIdx.x * 4 + (threadIdx.x >> 6);
    const int lane = threadIdx.x & 63;
    const int s = idx / nheads;
    const int hh = idx - s * nheads;
    const float* r = in + (long)s * inStride + inOff + hh * HDIM;
    const float x1 = r[lane];
    const float x2 = r[lane + 64];
    float ss = wave_sum(x1 * x1 + x2 * x2);
    const float inv = rsqrtf(ss * (1.f / HDIM) + EPSV);
    const float n1 = x1 * inv * ns[lane];
    const float n2 = x2 * inv * ns[lane + 64];
    const float c1 = cosT[s * HDIM + lane],      c2 = cosT[s * HDIM + 64 + lane];
    const float s1 = sinT[s * HDIM + lane],      s2 = sinT[s * HDIM + 64 + lane];
    const __hip_bfloat16 o1 = __float2bfloat16(n1 * c1 - n2 * s1);
    const __hip_bfloat16 o2 = __float2bfloat16(n2 * c2 + n1 * s2);
    for (int g = 0; g < rep; ++g) {
        __hip_bfloat16* w = out + ((long)(hh * rep + g) * SEQ + s) * HDIM;
        w[lane] = o1;
        w[lane + 64] = o2;
    }
}

// ---------------- V transpose+convert (strided f32 src -> vt [qhead][d][s] bf16, GQA-repeated) --------
__global__ void vtrans_k(const float* __restrict__ vf, int rowStride, int colOff,
                         __hip_bfloat16* __restrict__ vt) {
    __shared__ float tile[64][65];
    const int s0 = blockIdx.x * 64, d0 = blockIdx.y * 64, kv = blockIdx.z;
    const int lane = threadIdx.x & 63, part = threadIdx.x >> 6;
    for (int r = part; r < 64; r += 4)
        tile[r][lane] = vf[(long)(s0 + r) * rowStride + colOff + kv * HDIM + d0 + lane];
    __syncthreads();
    for (int r = part; r < 64; r += 4) {
        const __hip_bfloat16 b = __float2bfloat16(tile[lane][r]);
        const long o0 = ((long)(2 * kv) * HDIM + d0 + r) * SEQ + s0 + lane;
        vt[o0] = b;
        vt[o0 + (long)HDIM * SEQ] = b;  // GQA-repeated copy
    }
}

// ---------------- causal softmax: f32 raw scores -> bf16 probs ----------------
__global__ void softmax_k(const float* __restrict__ sc, __hip_bfloat16* __restrict__ pr) {
    const int i = blockIdx.x;
    const long base = ((long)blockIdx.y * SEQ + i) * SEQ;
    const float* row = sc + base;
    __hip_bfloat16* orow = pr + base;
    const int tid = threadIdx.x;
    const int n = i + 1;
    const float scale = 0.0883883476483184405f;  // 1/sqrt(128)
    float m = -3.0e38f;
    for (int j = tid; j < n; j += 256) m = fmaxf(m, row[j]);
    m = wave_max(m);
    __shared__ float sm[4], ssum[4];
    const int wid = tid >> 6, lane = tid & 63;
    if (lane == 0) sm[wid] = m;
    __syncthreads();
    m = fmaxf(fmaxf(sm[0], sm[1]), fmaxf(sm[2], sm[3])) * scale;
    float s = 0.f;
    for (int j = tid; j < n; j += 256) s += __expf(row[j] * scale - m);
    s = wave_sum(s);
    if (lane == 0) ssum[wid] = s;
    __syncthreads();
    s = ssum[0] + ssum[1] + ssum[2] + ssum[3];
    const float inv = 1.f / s;
    for (int j = tid; j < SEQ; j += 256) {
        const float p = (j < n) ? __expf(row[j] * scale - m) * inv : 0.f;
        orow[j] = __float2bfloat16(p);
    }
}

// ============== 8-wave counted-vmcnt GEMM (T3-coarse + T4) ==============
// C[M,N] = A[M,K] * B[N,K]^T.  A,B bf16 row-major, row stride exactly K.
// OUT: 0 = f32 C; 1 = bf16 C; 2 = f32 C = acc + f32 Res; 3 = bf16 C = silu(bf16 Res)*acc.
// 512 threads = 8 waves in 2(M)x4(N) grid. BK=64, double-buffered LDS.
// Key mechanism: raw s_barrier + counted s_waitcnt vmcnt(NLD) -- next tile's
// global_load_lds stay in flight across the barrier (never drain to 0).
template <int BM, int BN, int OUT>
__global__ __launch_bounds__(512)
void gemm8(const __hip_bfloat16* __restrict__ A, const __hip_bfloat16* __restrict__ B,
           void* __restrict__ Cv, const void* __restrict__ Resv,
           int K, int ldC) {
    constexpr int BK = 64;
    constexpr int WM = BM / 2, WN = BN / 4;
    constexpr int FM = WM / 16, FN = WN / 16;
    constexpr int CA = (BM * BK) / (512 * 8);   // 16B chunks per thread (A)
    constexpr int CB = (BN * BK) / (512 * 8);
    constexpr int NLD = CA + CB;                // this thread's loads per K-tile
    static_assert(CA >= 1 && CB >= 1, "tile too small");

    __shared__ __align__(16) __hip_bfloat16 sA[2][BM * BK];
    __shared__ __align__(16) __hip_bfloat16 sB[2][BN * BK];

    const int tid = threadIdx.x;
    const int lane = tid & 63;
    const int wid = tid >> 6;
    const int wr = wid >> 2;          // 0..1
    const int wc = wid & 3;           // 0..3

    const int row0 = blockIdx.y * BM;
    const int col0 = blockIdx.x * BN;

    f32x4 acc[FM][FN];
#pragma unroll
    for (int m = 0; m < FM; ++m)
#pragma unroll
        for (int n = 0; n < FN; ++n)
            acc[m][n] = (f32x4){0.f, 0.f, 0.f, 0.f};

    auto stage = [&](int buf, int kt) {
        const int k0 = kt * BK;
#pragma unroll
        for (int i = 0; i < CA; ++i) {
            const int c = i * 512 + tid;   // 16B chunk: row c>>3, col (c&7)*8
            gload16(A + (long)(row0 + (c >> 3)) * K + (k0 + (c & 7) * 8),
                    (char*)&sA[buf][0] + c * 16);
        }
#pragma unroll
        for (int i = 0; i < CB; ++i) {
            const int c = i * 512 + tid;
            gload16(B + (long)(col0 + (c >> 3)) * K + (k0 + (c & 7) * 8),
                    (char*)&sB[buf][0] + c * 16);
        }
    };

    const int nk = K / BK;
    stage(0, 0);

    for (int kt = 0; kt < nk; ++kt) {
        const int cur = kt & 1;
        if (kt + 1 < nk) {
            stage(cur ^ 1, kt + 1);   // issue next tile; stays in flight across barrier
            asm volatile("s_waitcnt vmcnt(%0)" :: "n"(NLD) : "memory");  // tile kt landed
        } else {
            asm volatile("s_waitcnt vmcnt(0)" ::: "memory");
        }
        __builtin_amdgcn_s_barrier();   // all waves: buf[cur] fully staged
        asm volatile("" ::: "memory");

#pragma unroll
        for (int ks = 0; ks < 2; ++ks) {
            bf16x8 af[FM], bfr[FN];
#pragma unroll
            for (int m = 0; m < FM; ++m)
                af[m] = *(const bf16x8*)&sA[cur][(wr * WM + m * 16 + (lane & 15)) * BK + ks * 32 + (lane >> 4) * 8];
#pragma unroll
            for (int n = 0; n < FN; ++n)
                bfr[n] = *(const bf16x8*)&sB[cur][(wc * WN + n * 16 + (lane & 15)) * BK + ks * 32 + (lane >> 4) * 8];
#pragma unroll
            for (int m = 0; m < FM; ++m)
#pragma unroll
                for (int n = 0; n < FN; ++n)
                    acc[m][n] = __builtin_amdgcn_mfma_f32_16x16x32_bf16(af[m], bfr[n], acc[m][n], 0, 0, 0);
        }

        asm volatile("" ::: "memory");
        __builtin_amdgcn_s_barrier();   // all waves done reading buf[cur] before next stage overwrites
    }

    // epilogue: C/D layout col = lane&15, row = (lane>>4)*4 + reg (m89-verified)
#pragma unroll
    for (int m = 0; m < FM; ++m) {
#pragma unroll
        for (int n = 0; n < FN; ++n) {
            const int rb = row0 + wr * WM + m * 16 + (lane >> 4) * 4;
            const int cc = col0 + wc * WN + n * 16 + (lane & 15);
#pragma unroll
            for (int j = 0; j < 4; ++j) {
                const long idx = (long)(rb + j) * ldC + cc;
                const float v = acc[m][n][j];
                if constexpr (OUT == 0) {
                    ((float*)Cv)[idx] = v;
                } else if constexpr (OUT == 1) {
                    ((__hip_bfloat16*)Cv)[idx] = __float2bfloat16(v);
                } else if constexpr (OUT == 2) {
                    ((float*)Cv)[idx] = v + ((const float*)Resv)[idx];
                } else {  // OUT == 3: silu(gate)*up, bf16 in-place
                    const float g = __bfloat162float(((const __hip_bfloat16*)Resv)[idx]);
                    const float sg = g / (1.f + __expf(-g));
                    ((__hip_bfloat16*)Cv)[idx] = __float2bfloat16(sg * v);
                }
            }
        }
    }
}

// ============== 4-wave double-buffered GEMM (attention scores / PV) ==============
// Unchanged from R3 (proven correct). OUT as above. KMODE: 1 causal block-skip,
// 2 causal K-truncation.
template <int BM, int BN, int OUT, int KMODE>
__global__ __launch_bounds__(256)
void gemm_db(const __hip_bfloat16* __restrict__ A, const __hip_bfloat16* __restrict__ B,
             void* __restrict__ Cv, const void* __restrict__ Resv,
             int K, int ldC, long strideA, long strideB, long strideC) {
    constexpr int BK = 64;
    constexpr int WM = BM / 2, WN = BN / 2;
    constexpr int FM = WM / 16, FN = WN / 16;
    constexpr int CA = (BM * BK) / (256 * 8);
    constexpr int CB = (BN * BK) / (256 * 8);
    static_assert(CA >= 1 && CB >= 1, "tile too small");

    __shared__ __align__(16) __hip_bfloat16 sA[2][BM * BK];
    __shared__ __align__(16) __hip_bfloat16 sB[2][BN * BK];

    const int tid = threadIdx.x;
    const int lane = tid & 63;
    const int wid = tid >> 6;
    const int wr = wid >> 1;
    const int wc = wid & 1;

    const int row0 = blockIdx.y * BM;
    const int col0 = blockIdx.x * BN;
    if (KMODE == 1 && row0 + BM - 1 < col0) return;

    const int bz = blockIdx.z;
    A += (long)bz * strideA;
    B += (long)bz * strideB;
    const long cOff = (long)bz * strideC;

    int nk = K / BK;
    if (KMODE == 2) { const int ke = row0 + BM; if (ke < K) nk = ke / BK; }

    f32x4 acc[FM][FN];
#pragma unroll
    for (int m = 0; m < FM; ++m)
#pragma unroll
        for (int n = 0; n < FN; ++n)
            acc[m][n] = (f32x4){0.f, 0.f, 0.f, 0.f};

    auto stage = [&](int buf, int kt) {
        const int k0 = kt * BK;
#pragma unroll
        for (int i = 0; i < CA; ++i) {
            const int c = i * 256 + tid;
            gload16(A + (long)(row0 + (c >> 3)) * K + (k0 + (c & 7) * 8),
                    (char*)&sA[buf][0] + c * 16);
        }
#pragma unroll
        for (int i = 0; i < CB; ++i) {
            const int c = i * 256 + tid;
            gload16(B + (long)(col0 + (c >> 3)) * K + (k0 + (c & 7) * 8),
                    (char*)&sB[buf][0] + c * 16);
        }
    };

    stage(0, 0);
    __syncthreads();

    int cur = 0;
    for (int kt = 0; kt < nk; ++kt) {
        if (kt + 1 < nk) stage(cur ^ 1, kt + 1);

        bf16x8 af[FM][2], bfr[FN][2];
#pragma unroll
        for (int ks = 0; ks < 2; ++ks) {
#pragma unroll
            for (int m = 0; m < FM; ++m)
                af[m][ks] = *(const bf16x8*)&sA[cur][(wr * WM + m * 16 + (lane & 15)) * BK + ks * 32 + (lane >> 4) * 8];
#pragma unroll
            for (int n = 0; n < FN; ++n)
                bfr[n][ks] = *(const bf16x8*)&sB[cur][(wc * WN + n * 16 + (lane & 15)) * BK + ks * 32 + (lane >> 4) * 8];
        }
#pragma unroll
        for (int ks = 0; ks < 2; ++ks)
#pragma unroll
            for (int m = 0; m < FM; ++m)
#pragma unroll
                for (int n = 0; n < FN; ++n)
                    acc[m][n] = __builtin_amdgcn_mfma_f32_16x16x32_bf16(af[m][ks], bfr[n][ks], acc[m][n], 0, 0, 0);

        __syncthreads();
        cur ^= 1;
    }

#pragma unroll
    for (int m = 0; m < FM; ++m) {
#pragma unroll
        for (int n = 0; n < FN; ++n) {
            const int rb = row0 + wr * WM + m * 16 + (lane >> 4) * 4;
            const int cc = col0 + wc * WN + n * 16 + (lane & 15);
#pragma unroll
            for (int j = 0; j < 4; ++j) {
                const long idx = cOff + (long)(rb + j) * ldC + cc;
                const float v = acc[m][n][j];
                if constexpr (OUT == 0) {
                    ((float*)Cv)[idx] = v;
                } else if constexpr (OUT == 1) {
                    ((__hip_bfloat16*)Cv)[idx] = __float2bfloat16(v);
                } else if constexpr (OUT == 2) {
                    ((float*)Cv)[idx] = v + ((const float*)Resv)[idx];
                } else {
                    const float g = __bfloat162float(((const __hip_bfloat16*)Resv)[idx]);
                    const float sg = g / (1.f + __expf(-g));
                    ((__hip_bfloat16*)Cv)[idx] = __float2bfloat16(sg * v);
                }
            }
        }
    }
}

// ---------------- host orchestration ----------------
extern "C" void kernel_launch(void* const* d_in, const int* in_sizes, int n_in,
                              void* d_out, int out_size, void* d_ws, size_t ws_size,
                              hipStream_t stream) {
    const int*   ids  = (const int*)d_in[0];
    const float* cosT = (const float*)d_in[2];
    const float* sinT = (const float*)d_in[3];
    const float* emb  = (const float*)d_in[4];
    const float* q_w  = (const float*)d_in[5];
    const float* k_w  = (const float*)d_in[6];
    const float* v_w  = (const float*)d_in[7];
    const float* o_w  = (const float*)d_in[8];
    const float* qn   = (const float*)d_in[9];
    const float* kn   = (const float*)d_in[10];
    const float* ln1  = (const float*)d_in[11];
    const float* ln2  = (const float*)d_in[12];
    const float* gw   = (const float*)d_in[13];
    const float* uw   = (const float*)d_in[14];
    const float* dw   = (const float*)d_in[15];

    char* W = (char*)d_ws;
    size_t off = 0;
    auto take = [&](size_t nb) { char* p = W + off; off += (nb + 255) & ~(size_t)255; return p; };

    // persistent bf16 weights (converted once per launch)
    __hip_bfloat16* wqkv = (__hip_bfloat16*) take((size_t)NLAYER * QKVN * DM * 2);
    __hip_bfloat16* wo   = (__hip_bfloat16*) take((size_t)NLAYER * DM * (NHEAD * HDIM) * 2);
    __hip_bfloat16* wg   = (__hip_bfloat16*) take((size_t)NLAYER * FFN * DM * 2);
    __hip_bfloat16* wu   = (__hip_bfloat16*) take((size_t)NLAYER * FFN * DM * 2);
    __hip_bfloat16* wd   = (__hip_bfloat16*) take((size_t)NLAYER * DM * FFN * 2);
    // activations
    float*          h      = (float*)          take((size_t)SEQ * DM * 4);
    __hip_bfloat16* x      = (__hip_bfloat16*) take((size_t)SEQ * DM * 2);
    float*          qkvf   = (float*)          take((size_t)SEQ * QKVN * 4);
    __hip_bfloat16* qb     = (__hip_bfloat16*) take((size_t)NHEAD * SEQ * HDIM * 2);
    __hip_bfloat16* kbr    = (__hip_bfloat16*) take((size_t)NHEAD * SEQ * HDIM * 2);
    __hip_bfloat16* vtr    = (__hip_bfloat16*) take((size_t)NHEAD * HDIM * SEQ * 2);
    __hip_bfloat16* ctx    = (__hip_bfloat16*) take((size_t)SEQ * NHEAD * HDIM * 2);
    float*          scores = (float*)          take((size_t)CHUNK * SEQ * SEQ * 4);
    __hip_bfloat16* probs  = (__hip_bfloat16*) take((size_t)CHUNK * SEQ * SEQ * 2);
    __hip_bfloat16* go     = (__hip_bfloat16*) take((size_t)SEQ * FFN * 2);
    if (off > ws_size) return;

    auto cvt = [&](const float* src, __hip_bfloat16* dst, long n) {
        cvt_bf16_k<<<(int)(n / 2048), 256, 0, stream>>>(src, dst);
    };

    // ---- convert all weights up front; QKV concatenated per layer ----
    for (int l = 0; l < NLAYER; ++l) {
        __hip_bfloat16* base = wqkv + (size_t)l * QKVN * DM;
        cvt(q_w + (size_t)l * (NHEAD * HDIM) * DM, base,                               (long)(NHEAD * HDIM) * DM);
        cvt(k_w + (size_t)l * (NKVH * HDIM) * DM,  base + (size_t)(NHEAD * HDIM) * DM, (long)(NKVH * HDIM) * DM);
        cvt(v_w + (size_t)l * (NKVH * HDIM) * DM,  base + (size_t)(NHEAD * HDIM + NKVH * HDIM) * DM, (long)(NKVH * HDIM) * DM);
    }
    cvt(o_w, wo, (long)NLAYER * DM * (NHEAD * HDIM));
    cvt(gw,  wg, (long)NLAYER * FFN * DM);
    cvt(uw,  wu, (long)NLAYER * FFN * DM);
    cvt(dw,  wd, (long)NLAYER * DM * FFN);

    embed_k<<<SEQ, 256, 0, stream>>>(ids, emb, h);

    for (int l = 0; l < NLAYER; ++l) {
        rmsnorm_k<<<SEQ, 256, 0, stream>>>(h, ln1 + l * DM, x);

        // fused QKV projection: [2048][4096] f32   (128x256 tile -> 256 blocks)
        gemm8<128, 256, 0><<<dim3(QKVN / 256, SEQ / 128), 512, 0, stream>>>(
            x, wqkv + (size_t)l * QKVN * DM, qkvf, nullptr, DM, QKVN);

        qknorm_rope_k<<<SEQ * NHEAD / 4, 256, 0, stream>>>(
            qkvf, QKVN, 0, qn + l * HDIM, cosT, sinT, qb, NHEAD, 1);
        qknorm_rope_k<<<SEQ * NKVH / 4, 256, 0, stream>>>(
            qkvf, QKVN, NHEAD * HDIM, kn + l * HDIM, cosT, sinT, kbr, NKVH, 2);
        vtrans_k<<<dim3(SEQ / 64, HDIM / 64, NKVH), 256, 0, stream>>>(
            qkvf, QKVN, NHEAD * HDIM + NKVH * HDIM, vtr);

        for (int c = 0; c < NHEAD / CHUNK; ++c) {
            gemm_db<128, 128, 0, 1><<<dim3(SEQ / 128, SEQ / 128, CHUNK), 256, 0, stream>>>(
                qb + (size_t)c * CHUNK * SEQ * HDIM,
                kbr + (size_t)c * CHUNK * SEQ * HDIM,
                scores, nullptr,
                HDIM, SEQ, (long)SEQ * HDIM, (long)SEQ * HDIM, (long)SEQ * SEQ);
            softmax_k<<<dim3(SEQ, CHUNK), 256, 0, stream>>>(scores, probs);
            gemm_db<128, 128, 1, 2><<<dim3(HDIM / 128, SEQ / 128, CHUNK), 256, 0, stream>>>(
                probs,
                vtr + (size_t)c * CHUNK * HDIM * SEQ,
                ctx + (size_t)c * CHUNK * HDIM, nullptr,
                SEQ, NHEAD * HDIM, (long)SEQ * SEQ, (long)HDIM * SEQ, (long)HDIM);
        }

        // O projection (128x128 -> 256 blocks)
        gemm8<128, 128, 2><<<dim3(DM / 128, SEQ / 128), 512, 0, stream>>>(
            ctx, wo + (size_t)l * DM * (NHEAD * HDIM), h, h, NHEAD * HDIM, DM);

        rmsnorm_k<<<SEQ, 256, 0, stream>>>(h, ln2 + l * DM, x);

        // gate / up (256x256 -> 192 blocks each)
        gemm8<256, 256, 1><<<dim3(FFN / 256, SEQ / 256), 512, 0, stream>>>(
            x, wg + (size_t)l * FFN * DM, go, nullptr, DM, FFN);
        gemm8<256, 256, 3><<<dim3(FFN / 256, SEQ / 256), 512, 0, stream>>>(
            x, wu + (size_t)l * FFN * DM, go, go, DM, FFN);   // go = silu(gate)*up
        // down (128x128 -> 256 blocks, K=6144)
        gemm8<128, 128, 2><<<dim3(DM / 128, SEQ / 128), 512, 0, stream>>>(
            go, wd + (size_t)l * DM * FFN, h, h, FFN, DM);
    }

    hipMemcpyAsync(d_out, h, (size_t)out_size * sizeof(float), hipMemcpyDeviceToDevice, stream);
}